// Round 2
// baseline (4276.971 us; speedup 1.0000x reference)
//
#include <hip/hip_runtime.h>
#include <hip/hip_bf16.h>

#define BB 256
#define SS 256
#define HH 512
#define KK 512
#define MM (BB*SS)            // 65536
#define CH 32                 // timesteps per chunk
#define NCHUNK (SS/CH)        // 8
#define CHROWS (CH*BB)        // 8192 rows per chunk GEMM
#define CHSZ ((long long)CHROWS*HH)   // elements per P slot per chunk

typedef __attribute__((ext_vector_type(4))) float f32x4;
typedef __attribute__((ext_vector_type(8))) short bf16x8;   // 8 bf16 in 4 VGPRs
typedef __attribute__((ext_vector_type(4))) int  int4v;

__device__ __forceinline__ float bf2f(unsigned short u){
  union { unsigned int i; float f; } w; w.i = ((unsigned int)u) << 16; return w.f;
}
__device__ __forceinline__ unsigned short f2bf(float f){
  union { float f; unsigned int i; } w; w.f = f;
  unsigned int x = w.i;
  x += 0x7fff + ((x >> 16) & 1);   // RNE
  return (unsigned short)(x >> 16);
}
__device__ __forceinline__ float sigf(float x){ return 1.f/(1.f+__expf(-x)); }
__device__ __forceinline__ float tanhf_(float x){
  x = fminf(fmaxf(x, -15.f), 15.f);
  float a = __expf(2.f*x);
  return (a - 1.f)/(a + 1.f);
}

// ---------------- pack x chunk -> bf16 [tl*BB+b][c] ----------------
__global__ void k_pack_x(const float* __restrict__ in, unsigned int* __restrict__ Xb32,
                         int t0){
  // each thread packs 2 columns (float2 is always 8B-aligned; float4 is not: row
  // byte base = row*2056+8)
  const long long tot2 = (long long)CHROWS*256;
  for (long long idx = (long long)blockIdx.x*blockDim.x + threadIdx.x; idx < tot2;
       idx += (long long)gridDim.x*blockDim.x){
    int r  = (int)(idx >> 8);        // tl*BB + b
    int c2 = (int)(idx & 255);       // column pair
    int b  = r & 255, tl = r >> 8;
    const float* src = in + ((long long)b*SS + t0 + tl)*514 + 2 + c2*2;
    float2 v = *(const float2*)src;
    unsigned int lo = f2bf(v.x), hi = f2bf(v.y);
    Xb32[(long long)r*256 + c2] = lo | (hi << 16);
  }
}

// ---------------- pack 12 weights, transposed to [n][k] bf16 ----------------
struct Ptr12 { const float* p[12]; };
__global__ void k_pack_w(Ptr12 ws, unsigned short* __restrict__ Wtall){
  int g = blockIdx.y;
  const float* W = ws.p[g];
  for (int idx = blockIdx.x*blockDim.x + threadIdx.x; idx < 512*512;
       idx += gridDim.x*blockDim.x){
    int n = idx >> 9, k = idx & 511;
    Wtall[(long long)g*262144 + idx] = f2bf(W[k*512 + n]);
  }
}

// ---------------- chunk GEMM: Xc(8192x512) @ Wcat(512x4096) + epilogue ----------------
struct EpiArgs {
  const float *b0,*b1,*b2,*b3,*b4,*b5,*b6,*b7;
  const float *Wt1,*Wt2,*Wd1,*Wd2,*Wto,*Wdo;
};

__launch_bounds__(256)
__global__ void k_gemm1(const unsigned short* __restrict__ Xb,
                        const unsigned short* __restrict__ Wtall,
                        unsigned short* __restrict__ P,
                        EpiArgs ea, const float* __restrict__ in, int t0){
  __shared__ unsigned short As[64][40];   // +8 pad
  __shared__ unsigned short Bs[64][40];
  int tid  = threadIdx.x;
  int m0   = blockIdx.y * 64;          // row in chunk (0..8191)
  int n0   = blockIdx.x * 64;          // column in 8*512 concatenated space
  int g    = n0 >> 9;                  // gate, block-uniform
  int lane = tid & 63;
  int w    = tid >> 6;
  int wrow = w >> 1, wcol = w & 1;
  int r16  = lane & 15, kb = (lane >> 4) * 8;
  int ldrow = tid >> 2;
  int ldk   = (tid & 3) * 8;

  f32x4 acc[2][2] = {};
  for (int k0 = 0; k0 < KK; k0 += 32){
    __syncthreads();
    *(int4v*)&As[ldrow][ldk] = *(const int4v*)&Xb[(long long)(m0+ldrow)*KK + k0 + ldk];
    *(int4v*)&Bs[ldrow][ldk] = *(const int4v*)&Wtall[(long long)(n0+ldrow)*KK + k0 + ldk];
    __syncthreads();
    bf16x8 a0 = *(const bf16x8*)&As[wrow*32 +      r16][kb];
    bf16x8 a1 = *(const bf16x8*)&As[wrow*32 + 16 + r16][kb];
    bf16x8 b0 = *(const bf16x8*)&Bs[wcol*32 +      r16][kb];
    bf16x8 b1 = *(const bf16x8*)&Bs[wcol*32 + 16 + r16][kb];
    acc[0][0] = __builtin_amdgcn_mfma_f32_16x16x32_bf16(a0,b0,acc[0][0],0,0,0);
    acc[0][1] = __builtin_amdgcn_mfma_f32_16x16x32_bf16(a0,b1,acc[0][1],0,0,0);
    acc[1][0] = __builtin_amdgcn_mfma_f32_16x16x32_bf16(a1,b0,acc[1][0],0,0,0);
    acc[1][1] = __builtin_amdgcn_mfma_f32_16x16x32_bf16(a1,b1,acc[1][1],0,0,0);
  }

  const float* bias = (g==0)?ea.b0:(g==1)?ea.b1:(g==2)?ea.b2:(g==3)?ea.b3:
                      (g==4)?ea.b4:(g==5)?ea.b5:(g==6)?ea.b6:ea.b7;
  unsigned short* Pg = P + (long long)g*CHSZ;
  for (int r = 0; r < 2; r++)
    for (int c = 0; c < 2; c++)
      for (int i = 0; i < 4; i++){
        int rr   = m0 + wrow*32 + r*16 + (lane>>4)*4 + i;   // C/D: row=(lane>>4)*4+reg
        int ncat = n0 + wcol*32 + c*16 + r16;               //      col=lane&15
        int h = ncat & 511;
        float v = acc[r][c][i] + bias[h];
        if (g >= 3){
          int b = rr & 255, tl = rr >> 8;
          long long inrow = ((long long)b*SS + t0 + tl)*514;
          if      (g==3) v += sigf(in[inrow]  *ea.Wt1[h]);
          else if (g==4) v += sigf(in[inrow]  *ea.Wt2[h]);
          else if (g==5) v += sigf(in[inrow+1]*ea.Wd1[h]);
          else if (g==6) v += sigf(in[inrow+1]*ea.Wd2[h]);
          else           v += in[inrow]*ea.Wto[h] + in[inrow+1]*ea.Wdo[h];
        }
        Pg[(long long)rr*HH + h] = f2bf(v);   // layout [tl][b][h]
      }
}

// ---------------- combine: G1 = sig(pt1)*sig(pd1) -> slot3, G2 -> slot4 ----------------
__global__ void k_combine(unsigned short* __restrict__ P){
  unsigned short* P3 = P + 3*CHSZ;
  unsigned short* P4 = P + 4*CHSZ;
  const unsigned short* P5 = P + 5*CHSZ;
  const unsigned short* P6 = P + 6*CHSZ;
  for (long long i = (long long)blockIdx.x*blockDim.x + threadIdx.x; i < CHSZ;
       i += (long long)gridDim.x*blockDim.x){
    float t1 = sigf(bf2f(P3[i])), d1 = sigf(bf2f(P5[i]));
    float t2 = sigf(bf2f(P4[i])), d2 = sigf(bf2f(P6[i]));
    P3[i] = f2bf(t1*d1);
    P4[i] = f2bf(t2*d2);
  }
}

// ---------------- step: h@[Whi|Whf|Whc|Who] + cell update ----------------
// 128 blocks: mt = bid>>4 (8 x 32 rows), ht = bid&15 (16 x 32 cols). 4 waves = 4 gates.
__launch_bounds__(256)
__global__ void k_step(const unsigned short* __restrict__ Hprev,
                       unsigned short* __restrict__ Hnext,
                       float* __restrict__ C,
                       const unsigned short* __restrict__ Whall,
                       const unsigned short* __restrict__ P,
                       float* __restrict__ out, int t, int tl){
  __shared__ float sg[4][32][32];
  int tid  = threadIdx.x;
  int mt   = blockIdx.x >> 4, ht = blockIdx.x & 15;
  int m0   = mt*32, h0 = ht*32;
  int lane = tid & 63, g = tid >> 6;
  int r16  = lane & 15, kb = (lane >> 4) * 8;

  f32x4 acc[2][2] = {};
  const unsigned short* Wg = Whall + (long long)g*HH*KK;
#pragma unroll 4
  for (int k0 = 0; k0 < KK; k0 += 32){
    bf16x8 a[2], b[2];
    for (int r = 0; r < 2; r++)
      a[r] = *(const bf16x8*)&Hprev[(long long)(m0 + r*16 + r16)*KK + k0 + kb];
    for (int c = 0; c < 2; c++)
      b[c] = *(const bf16x8*)&Wg[(long long)(h0 + c*16 + r16)*KK + k0 + kb];
    for (int r = 0; r < 2; r++)
      for (int c = 0; c < 2; c++)
        acc[r][c] = __builtin_amdgcn_mfma_f32_16x16x32_bf16(a[r],b[c],acc[r][c],0,0,0);
  }
  for (int r = 0; r < 2; r++)
    for (int c = 0; c < 2; c++)
      for (int i = 0; i < 4; i++)
        sg[g][r*16 + (lane>>4)*4 + i][c*16 + r16] = acc[r][c][i];
  __syncthreads();

  int mb = tid >> 3, hh0 = (tid & 7) * 4;
  int bb = m0 + mb;
  const unsigned short* P0  = P;
  const unsigned short* P1  = P + 1*CHSZ;
  const unsigned short* P2  = P + 2*CHSZ;
  const unsigned short* PG1 = P + 3*CHSZ;
  const unsigned short* PG2 = P + 4*CHSZ;
  const unsigned short* P7  = P + 7*CHSZ;
  long long pbase = ((long long)tl*BB + bb)*HH + h0 + hh0;
  long long cbase = (long long)bb*HH + h0 + hh0;
  for (int j = 0; j < 4; j++){
    long long p = pbase + j;
    float it = sigf(bf2f(P0[p]) + sg[0][mb][hh0+j]);
    float ft = sigf(bf2f(P1[p]) + sg[1][mb][hh0+j]);
    float jj = tanhf_(bf2f(P2[p]) + sg[2][mb][hh0+j]);
    float ot = sigf(bf2f(P7[p]) + sg[3][mb][hh0+j]);
    float g1 = bf2f(PG1[p]), g2 = bf2f(PG2[p]);
    float co = C[cbase + j];
    float chat = ft*co + it*g1*jj;
    float cnew = ft*co + it*g2*jj;
    float hn = ot * tanhf_(chat);
    C[cbase + j] = cnew;
    Hnext[cbase + j] = f2bf(hn);
    out[((long long)bb*SS + t)*HH + h0 + hh0 + j] = hn;
    if (t == SS-1){
      out[(long long)MM*HH + cbase + j] = hn;                        // h_t
      out[(long long)MM*HH + (long long)BB*HH + cbase + j] = cnew;   // c_t
    }
  }
}

extern "C" void kernel_launch(void* const* d_in, const int* in_sizes, int n_in,
                              void* d_out, int out_size, void* d_ws, size_t ws_size,
                              hipStream_t stream){
  const float* in = (const float*)d_in[0];

  // workspace carve (~80 MB total)
  unsigned short* Wtall = (unsigned short*)d_ws;          // 12*512*512 bf16 (8 Wx + 4 Wh, [n][k])
  unsigned short* Xb    = Wtall + 12LL*512*512;           // CHROWS*KK bf16
  unsigned short* P     = Xb + (long long)CHROWS*KK;      // 8 * CHSZ bf16
  float* C  = (float*)(P + 8*CHSZ);                       // BB*HH fp32
  unsigned short* Hb0 = (unsigned short*)(C + (long long)BB*HH);
  unsigned short* Hb1 = Hb0 + (long long)BB*HH;

  hipMemsetAsync(C,   0, (size_t)BB*HH*4, stream);
  hipMemsetAsync(Hb0, 0, (size_t)BB*HH*2, stream);

  Ptr12 pw;
  pw.p[0]  = (const float*)d_in[1];   // Wxi
  pw.p[1]  = (const float*)d_in[4];   // Wxf
  pw.p[2]  = (const float*)d_in[7];   // Wxc
  pw.p[3]  = (const float*)d_in[10];  // Wxt1
  pw.p[4]  = (const float*)d_in[13];  // Wxt2
  pw.p[5]  = (const float*)d_in[16];  // Wxd1
  pw.p[6]  = (const float*)d_in[19];  // Wxd2
  pw.p[7]  = (const float*)d_in[22];  // Wxo
  pw.p[8]  = (const float*)d_in[2];   // Whi
  pw.p[9]  = (const float*)d_in[5];   // Whf
  pw.p[10] = (const float*)d_in[8];   // Whc
  pw.p[11] = (const float*)d_in[23];  // Who
  k_pack_w<<<dim3(64,12), 256, 0, stream>>>(pw, Wtall);

  EpiArgs ea;
  ea.b0 = (const float*)d_in[3];  ea.b1 = (const float*)d_in[6];
  ea.b2 = (const float*)d_in[9];  ea.b3 = (const float*)d_in[12];
  ea.b4 = (const float*)d_in[15]; ea.b5 = (const float*)d_in[18];
  ea.b6 = (const float*)d_in[21]; ea.b7 = (const float*)d_in[26];
  ea.Wt1 = (const float*)d_in[11]; ea.Wt2 = (const float*)d_in[14];
  ea.Wd1 = (const float*)d_in[17]; ea.Wd2 = (const float*)d_in[20];
  ea.Wto = (const float*)d_in[24]; ea.Wdo = (const float*)d_in[25];

  const unsigned short* Whall = Wtall + 8LL*512*512;
  float* out = (float*)d_out;

  for (int ck = 0; ck < NCHUNK; ck++){
    int t0 = ck*CH;
    k_pack_x<<<2048, 256, 0, stream>>>(in, (unsigned int*)Xb, t0);
    k_gemm1<<<dim3(64, CHROWS/64), 256, 0, stream>>>(Xb, Wtall, P, ea, in, t0);
    k_combine<<<2048, 256, 0, stream>>>(P);
    for (int tl = 0; tl < CH; tl++){
      int t = t0 + tl;
      const unsigned short* Hp = (t & 1) ? Hb1 : Hb0;
      unsigned short*       Hn = (t & 1) ? Hb0 : Hb1;
      k_step<<<128, 256, 0, stream>>>(Hp, Hn, C, Whall, P, out, t, tl);
    }
  }
}